// Round 2
// baseline (655.460 us; speedup 1.0000x reference)
//
#include <hip/hip_runtime.h>
#include <hip/hip_bf16.h>
#include <cstdint>
#include <cstddef>

typedef unsigned short u16;
typedef short v8s __attribute__((ext_vector_type(8)));   // 8 bf16 payloads (4 VGPRs)
typedef float v4f __attribute__((ext_vector_type(4)));
typedef __hip_bfloat16 bf16;

// B=4, N=1024, D=1024, H=8, DK=DV=128
#define PROJ_ELEMS  4194304ull        // 4096*1024
#define AT_ELEMS    33554432ull       // 4*8*1024*1024
#define INV_TEMP    0.08838834764831845f

__device__ __forceinline__ void store_out(float* p, float v) { *p = v; }
__device__ __forceinline__ void store_out(bf16* p, float v) { *p = __float2bfloat16(v); }

// load 8 contiguous source elements as a bf16x8 fragment
__device__ __forceinline__ v8s load8(const u16* p) { return *(const v8s*)p; }
__device__ __forceinline__ v8s load8(const float* p) {
    const float4 a = *(const float4*)p;
    const float4 b = *(const float4*)(p + 4);
    v8s r;
    bf16 t;
    t = __float2bfloat16(a.x); r[0] = *(const short*)&t;
    t = __float2bfloat16(a.y); r[1] = *(const short*)&t;
    t = __float2bfloat16(a.z); r[2] = *(const short*)&t;
    t = __float2bfloat16(a.w); r[3] = *(const short*)&t;
    t = __float2bfloat16(b.x); r[4] = *(const short*)&t;
    t = __float2bfloat16(b.y); r[5] = *(const short*)&t;
    t = __float2bfloat16(b.z); r[6] = *(const short*)&t;
    t = __float2bfloat16(b.w); r[7] = *(const short*)&t;
    return r;
}

// ---------------------------------------------------------------------------
// Generic batched MFMA GEMM:  C[M,N] = alpha * A[M,K] @ B[N,K]^T
// A/B may be fp32 (converted to bf16 during staging) or bf16 (u16).
// grid = (N/128, M/128, batches); block = 256 (4 waves, each computing 64x64).
// batch z decomposed as (z/batDiv, z%batDiv) with separate strides.
// ---------------------------------------------------------------------------
template <typename AT, typename BT, typename OutT>
__global__ __launch_bounds__(256, 2)
void gemm_bt(const AT* __restrict__ A, const BT* __restrict__ B, OutT* __restrict__ C,
             int K, long long lda, long long ldb, long long ldc,
             int batDiv,
             long long sAo, long long sAi, long long sBo, long long sBi,
             long long sCo, long long sCi, float alpha)
{
    __shared__ __align__(16) u16 sA[128][40];   // stride 80B = 5x16B: aligned, non-pow2
    __shared__ __align__(16) u16 sB[128][40];

    const int z  = blockIdx.z;
    const int zo = z / batDiv;
    const int zi = z - zo * batDiv;
    const AT* Ab = A + (size_t)zo * (size_t)sAo + (size_t)zi * (size_t)sAi;
    const BT* Bb = B + (size_t)zo * (size_t)sBo + (size_t)zi * (size_t)sBi;
    OutT*     Cb = C + (size_t)zo * (size_t)sCo + (size_t)zi * (size_t)sCi;

    const int m0 = blockIdx.y * 128;
    const int n0 = blockIdx.x * 128;
    const int tid  = threadIdx.x;
    const int lane = tid & 63;
    const int wid  = tid >> 6;
    const int wm = (wid >> 1) * 64;   // wave row offset in tile
    const int wn = (wid & 1) * 64;    // wave col offset in tile
    const int quad = lane >> 4;
    const int l16  = lane & 15;

    v4f acc[4][4];
    #pragma unroll
    for (int i = 0; i < 4; ++i)
        #pragma unroll
        for (int j = 0; j < 4; ++j)
            acc[i][j] = (v4f){0.f, 0.f, 0.f, 0.f};

    for (int k0 = 0; k0 < K; k0 += 32) {
        // stage 128x32 bf16 A-tile and B-tile
        #pragma unroll
        for (int it = 0; it < 2; ++it) {
            int slot = tid + it * 256;
            int row  = slot >> 2;
            int cg   = (slot & 3) << 3;
            *(v8s*)&sA[row][cg] = load8(Ab + (size_t)(m0 + row) * (size_t)lda + (size_t)(k0 + cg));
            *(v8s*)&sB[row][cg] = load8(Bb + (size_t)(n0 + row) * (size_t)ldb + (size_t)(k0 + cg));
        }
        __syncthreads();

        // fragments: A[m=lane&15][k=quad*8+j]; B mirrors A for the Bt form
        v8s af[4], bfr[4];
        #pragma unroll
        for (int i = 0; i < 4; ++i) {
            af[i]  = *(const v8s*)&sA[wm + i * 16 + l16][quad * 8];
            bfr[i] = *(const v8s*)&sB[wn + i * 16 + l16][quad * 8];
        }
        #pragma unroll
        for (int i = 0; i < 4; ++i)
            #pragma unroll
            for (int j = 0; j < 4; ++j)
                acc[i][j] = __builtin_amdgcn_mfma_f32_16x16x32_bf16(af[i], bfr[j], acc[i][j], 0, 0, 0);
        __syncthreads();
    }

    // C/D layout (m89-verified): col = lane&15, row = quad*4 + reg
    #pragma unroll
    for (int i = 0; i < 4; ++i) {
        int rbase = m0 + wm + i * 16 + quad * 4;
        #pragma unroll
        for (int j = 0; j < 4; ++j) {
            int gcol = n0 + wn + j * 16 + l16;
            #pragma unroll
            for (int r = 0; r < 4; ++r)
                store_out(&Cb[(size_t)(rbase + r) * (size_t)ldc + (size_t)gcol],
                          acc[i][j][r] * alpha);
        }
    }
}

// ---------------------------------------------------------------------------
// Batched transpose of one projection (bf16 ws -> bf16 ws):
// per z=(b*8+h), in-view [1024 m][128 d] (row stride 1024, base b*2^20+h*128)
// -> out [z][128 d][1024 m] contiguous.  grid (32,4,32); block (32,8)
// ---------------------------------------------------------------------------
__global__ __launch_bounds__(256)
void transpose_proj(const u16* __restrict__ in, u16* __restrict__ out)
{
    __shared__ u16 tile[32][33];
    const int z = blockIdx.z;
    const int b = z >> 3, h = z & 7;
    const u16* ib = in + (size_t)b * 1048576ull + (size_t)h * 128ull;
    u16* ob = out + (size_t)z * 131072ull;
    const int m0 = blockIdx.x * 32;
    const int d0 = blockIdx.y * 32;
    const int tx = threadIdx.x;
    const int ty = threadIdx.y;
    #pragma unroll
    for (int i = 0; i < 4; ++i)
        tile[ty + i * 8][tx] = ib[(size_t)(m0 + ty + i * 8) * 1024ull + (size_t)(d0 + tx)];
    __syncthreads();
    #pragma unroll
    for (int i = 0; i < 4; ++i)
        ob[(size_t)(d0 + ty + i * 8) * 1024ull + (size_t)(m0 + tx)] = tile[tx][ty + i * 8];
}

// ---------------------------------------------------------------------------
// Masked softmax over attn_time logits, fp32 in-place in the output region.
// One block per row (32768 rows of 1024). Row r = (b*8+h)*1024 + n.
// ---------------------------------------------------------------------------
__global__ __launch_bounds__(256)
void softmax_time(float* __restrict__ P, const int* __restrict__ mask)
{
    const int r  = blockIdx.x;
    const int bh = r >> 10, n = r & 1023;
    const int b  = bh >> 3;
    float* prow = P + (size_t)r * 1024ull;
    const int* mrow = mask + ((size_t)b * 1024ull + (size_t)n) * 1024ull;
    const int t = threadIdx.x;

    float x[4];
    float mx = -3.4e38f;
    #pragma unroll
    for (int i = 0; i < 4; ++i) {
        int c = t + i * 256;
        float v = prow[c];
        v = (mrow[c] == 0) ? -1e9f : v;
        x[i] = v;
        mx = fmaxf(mx, v);
    }
    #pragma unroll
    for (int o = 32; o; o >>= 1) mx = fmaxf(mx, __shfl_xor(mx, o));
    __shared__ float redm[4], reds[4];
    const int w = t >> 6;
    if ((t & 63) == 0) redm[w] = mx;
    __syncthreads();
    mx = fmaxf(fmaxf(redm[0], redm[1]), fmaxf(redm[2], redm[3]));

    float s = 0.f;
    #pragma unroll
    for (int i = 0; i < 4; ++i) { x[i] = __expf(x[i] - mx); s += x[i]; }
    #pragma unroll
    for (int o = 32; o; o >>= 1) s += __shfl_xor(s, o);
    if ((t & 63) == 0) reds[w] = s;
    __syncthreads();
    s = reds[0] + reds[1] + reds[2] + reds[3];
    const float inv = 1.f / s;
    #pragma unroll
    for (int i = 0; i < 4; ++i)
        prow[t + i * 256] = x[i] * inv;
}

// ---------------------------------------------------------------------------
// Feature softmax: F fp32 [4096 rows][128] (row r = z*128 + d), softmax over
// last dim -> fp32 attn_feature output AND transposed bf16 FT[z][e][d].
// One block (128 thr) per row.
// ---------------------------------------------------------------------------
__global__ __launch_bounds__(128)
void softmax_feat(const float* __restrict__ F, float* __restrict__ out_af, u16* __restrict__ FT)
{
    const int r = blockIdx.x;
    const int z = r >> 7, d = r & 127;
    const int e = threadIdx.x;
    float x = F[(size_t)r * 128ull + e];
    float mx = x;
    #pragma unroll
    for (int o = 32; o; o >>= 1) mx = fmaxf(mx, __shfl_xor(mx, o));
    __shared__ float redm[2], reds[2];
    const int w = e >> 6;
    if ((e & 63) == 0) redm[w] = mx;
    __syncthreads();
    mx = fmaxf(redm[0], redm[1]);
    float ex = __expf(x - mx);
    float s = ex;
    #pragma unroll
    for (int o = 32; o; o >>= 1) s += __shfl_xor(s, o);
    if ((e & 63) == 0) reds[w] = s;
    __syncthreads();
    s = reds[0] + reds[1];
    float p = ex / s;
    out_af[(size_t)r * 128ull + e] = p;
    bf16 pb = __float2bfloat16(p);
    FT[(size_t)z * 16384ull + (size_t)e * 128ull + d] = *(const u16*)&pb;
}

// ---------------------------------------------------------------------------
// out = LayerNorm(fc + v) * gamma + beta ; one block per row (4096 x 1024)
// ---------------------------------------------------------------------------
__global__ __launch_bounds__(256)
void resid_ln(const float* __restrict__ fc, const float* __restrict__ v,
              const float* __restrict__ gamma, const float* __restrict__ beta,
              float* __restrict__ out)
{
    const int r = blockIdx.x;
    const int t = threadIdx.x;
    const float* fr = fc + (size_t)r * 1024ull;
    const float* vr = v  + (size_t)r * 1024ull;
    float x[4], s = 0.f, s2 = 0.f;
    #pragma unroll
    for (int i = 0; i < 4; ++i) {
        int c = t + i * 256;
        float xv = fr[c] + vr[c];
        x[i] = xv; s += xv; s2 += xv * xv;
    }
    #pragma unroll
    for (int o = 32; o; o >>= 1) { s += __shfl_xor(s, o); s2 += __shfl_xor(s2, o); }
    __shared__ float rs[4], rs2[4];
    const int w = t >> 6;
    if ((t & 63) == 0) { rs[w] = s; rs2[w] = s2; }
    __syncthreads();
    s  = rs[0] + rs[1] + rs[2] + rs[3];
    s2 = rs2[0] + rs2[1] + rs2[2] + rs2[3];
    const float mean = s * (1.f / 1024.f);
    const float var  = s2 * (1.f / 1024.f) - mean * mean;
    const float rstd = rsqrtf(var + 1e-6f);
    #pragma unroll
    for (int i = 0; i < 4; ++i) {
        int c = t + i * 256;
        out[(size_t)r * 1024ull + c] = (x[i] - mean) * rstd * gamma[c] + beta[c];
    }
}

// ---------------------------------------------------------------------------
extern "C" void kernel_launch(void* const* d_in, const int* in_sizes, int n_in,
                              void* d_out, int out_size, void* d_ws, size_t ws_size,
                              hipStream_t stream)
{
    (void)in_sizes; (void)n_in; (void)out_size; (void)ws_size;
    // inputs: fp32 tensors (per reference), mask int32
    const float* q_time    = (const float*)d_in[0];
    const float* k_time    = (const float*)d_in[1];
    const float* q_feature = (const float*)d_in[2];
    const float* k_feature = (const float*)d_in[3];
    const float* v_in      = (const float*)d_in[4];
    const int*   mask      = (const int*)d_in[5];
    const float* w_qs_t    = (const float*)d_in[6];
    const float* w_ks_t    = (const float*)d_in[7];
    const float* w_qs_f    = (const float*)d_in[8];
    const float* w_ks_f    = (const float*)d_in[9];
    const float* w_vs      = (const float*)d_in[10];
    const float* w_fc      = (const float*)d_in[11];
    const float* gamma     = (const float*)d_in[12];
    const float* beta      = (const float*)d_in[13];

    // workspace layout (99 MB total); intermediates bf16 except F/fc fp32
    char* ws = (char*)d_ws;
    const size_t MB = 1ull << 20;
    u16*   qt  = (u16*)(ws + 0  * MB);   // [4096,1024] bf16 projections
    u16*   kt  = (u16*)(ws + 8  * MB);
    u16*   qf  = (u16*)(ws + 16 * MB);
    u16*   kf  = (u16*)(ws + 24 * MB);
    u16*   vv  = (u16*)(ws + 32 * MB);
    u16*   vvT = (u16*)(ws + 40 * MB);   // [32][128][1024] bf16
    u16*   qfT = (u16*)(ws + 48 * MB);
    u16*   kfT = (u16*)(ws + 56 * MB);
    u16*   FT  = (u16*)(ws + 64 * MB);   // [32][128e][128d] bf16
    float* F   = (float*)(ws + 65 * MB); // [32][128][128] fp32 feature logits
    u16*   opv = (u16*)(ws + 67 * MB);   // [32][1024][128] bf16
    u16*   o2  = (u16*)(ws + 75 * MB);   // [4096][1024] bf16 ([b,n,h,e])
    float* fc  = (float*)(ws + 83 * MB); // [4096][1024] fp32 ..99MB

    float* out0 = (float*)d_out;
    float* oAT  = out0 + PROJ_ELEMS;              // attn_time [4,8,1024,1024] fp32
    float* oAF  = out0 + PROJ_ELEMS + AT_ELEMS;   // attn_feature [4,8,128,128] fp32

    const dim3 blk(256);

    // 1) five projections: fp32 [4096,1024] @ fp32 [1024,1024]^T -> bf16
    {
        dim3 g(8, 32, 1);
        gemm_bt<<<g, blk, 0, stream>>>(q_time,    w_qs_t, (bf16*)qt, 1024, 1024, 1024, 1024, 1, 0,0,0,0,0,0, 1.f);
        gemm_bt<<<g, blk, 0, stream>>>(k_time,    w_ks_t, (bf16*)kt, 1024, 1024, 1024, 1024, 1, 0,0,0,0,0,0, 1.f);
        gemm_bt<<<g, blk, 0, stream>>>(q_feature, w_qs_f, (bf16*)qf, 1024, 1024, 1024, 1024, 1, 0,0,0,0,0,0, 1.f);
        gemm_bt<<<g, blk, 0, stream>>>(k_feature, w_ks_f, (bf16*)kf, 1024, 1024, 1024, 1024, 1, 0,0,0,0,0,0, 1.f);
        gemm_bt<<<g, blk, 0, stream>>>(v_in,      w_vs,   (bf16*)vv, 1024, 1024, 1024, 1024, 1, 0,0,0,0,0,0, 1.f);
    }

    // 2) transposes: vv,qf,kf per-(b,h) [1024,128] -> [128,1024]
    {
        dim3 tg(32, 4, 32), tb(32, 8, 1);
        transpose_proj<<<tg, tb, 0, stream>>>(vv, vvT);
        transpose_proj<<<tg, tb, 0, stream>>>(qf, qfT);
        transpose_proj<<<tg, tb, 0, stream>>>(kf, kfT);
    }

    // 3) time logits: per (b,h) qt[1024,128] @ kt[1024,128]^T * 1/temp -> fp32 oAT
    {
        dim3 g(8, 8, 32);
        gemm_bt<<<g, blk, 0, stream>>>((const u16*)qt, (const u16*)kt, oAT, 128, 1024, 1024, 1024, 8,
            1048576, 128, 1048576, 128, 8388608, 1048576, INV_TEMP);
    }
    // 4) masked softmax in place (fp32)
    softmax_time<<<32768, 256, 0, stream>>>(oAT, mask);

    // 5) feature logits: per z qfT[128,1024] @ kfT[128,1024]^T * 1/temp -> F fp32
    {
        dim3 g(1, 1, 32);
        gemm_bt<<<g, blk, 0, stream>>>((const u16*)qfT, (const u16*)kfT, F, 1024, 1024, 1024, 128, 1,
            131072, 0, 131072, 0, 16384, 0, INV_TEMP);
    }
    // 6) feature softmax -> fp32 oAF + transposed bf16 FT
    softmax_feat<<<4096, 128, 0, stream>>>(F, oAF, FT);

    // 7) PV: per z P(fp32)[1024,1024] @ vvT[128,1024]^T -> opv[1024,128] bf16
    {
        dim3 g(1, 8, 32);
        gemm_bt<<<g, blk, 0, stream>>>((const float*)oAT, (const u16*)vvT, (bf16*)opv, 1024,
            1024, 1024, 128, 1, 1048576, 0, 131072, 0, 131072, 0, 1.f);
    }
    // 8) out2: per z=(b,h) opv[1024,128] @ FT[128,128]^T -> [b,n,h,e] bf16
    {
        dim3 g(1, 8, 32);
        gemm_bt<<<g, blk, 0, stream>>>((const u16*)opv, (const u16*)FT, (bf16*)o2, 128,
            128, 128, 1024, 8, 1048576, 131072, 131072, 16384, 1048576, 128, 1.f);
    }
    // 9) fc: o2(bf16) [4096,1024] @ w_fc(fp32)[1024,1024]^T -> fp32
    {
        dim3 g(8, 32, 1);
        gemm_bt<<<g, blk, 0, stream>>>((const u16*)o2, w_fc, fc, 1024, 1024, 1024, 1024, 1,
            0, 0, 0, 0, 0, 0, 1.f);
    }
    // 10) residual + LayerNorm -> out0 (fp32)
    resid_ln<<<4096, 256, 0, stream>>>(fc, v_in, gamma, beta, out0);
}

// Round 3
// 496.250 us; speedup vs baseline: 1.3208x; 1.3208x over previous
//
#include <hip/hip_runtime.h>
#include <hip/hip_bf16.h>
#include <cstdint>
#include <cstddef>

typedef unsigned short u16;
typedef short v8s __attribute__((ext_vector_type(8)));   // 8 bf16 payloads (4 VGPRs)
typedef float v4f __attribute__((ext_vector_type(4)));
typedef __hip_bfloat16 bf16;

// B=4, N=1024, D=1024, H=8, DK=DV=128
#define PROJ_ELEMS  4194304ull        // 4096*1024
#define AT_ELEMS    33554432ull       // 4*8*1024*1024
#define INV_TEMP    0.08838834764831845f

__device__ __forceinline__ void store_out(float* p, float v) { *p = v; }
__device__ __forceinline__ void store_out(bf16* p, float v) { *p = __float2bfloat16(v); }

// load 8 contiguous fp32 elements, convert to bf16x8 fragment
__device__ __forceinline__ v8s load8f(const float* p) {
    const float4 a = *(const float4*)p;
    const float4 b = *(const float4*)(p + 4);
    v8s r;
    bf16 t;
    t = __float2bfloat16(a.x); r[0] = *(const short*)&t;
    t = __float2bfloat16(a.y); r[1] = *(const short*)&t;
    t = __float2bfloat16(a.z); r[2] = *(const short*)&t;
    t = __float2bfloat16(a.w); r[3] = *(const short*)&t;
    t = __float2bfloat16(b.x); r[4] = *(const short*)&t;
    t = __float2bfloat16(b.y); r[5] = *(const short*)&t;
    t = __float2bfloat16(b.z); r[6] = *(const short*)&t;
    t = __float2bfloat16(b.w); r[7] = *(const short*)&t;
    return r;
}

// ---------------------------------------------------------------------------
// MFMA GEMM core:  C[128,128 tile] = alpha * A[M,K] @ B[N,K]^T
// B always bf16, staged via global_load_lds width=16 (m97 fast path).
// A bf16 -> global_load_lds; A fp32 -> float4 loads + cvt + ds_write_b128.
// LDS tiles UNPADDED [128][32]: byte offset slot*16 == wave-uniform base +
// lane*16, as the global_load_lds contract requires (m104/m108).
// block = 256 threads (4 waves, each computing a 64x64 quadrant).
// ---------------------------------------------------------------------------
template <typename AT, typename OutT>
__device__ __forceinline__ void gemm_core(
    const AT* __restrict__ Ab, const u16* __restrict__ Bb, OutT* __restrict__ Cb,
    int K, int lda, int ldb, int ldc, float alpha, int m0, int n0)
{
    __shared__ __align__(16) u16 sA[128][32];
    __shared__ __align__(16) u16 sB[128][32];

    const int tid  = threadIdx.x;
    const int lane = tid & 63;
    const int wid  = tid >> 6;
    const int wm = (wid >> 1) * 64;   // wave row offset in tile
    const int wn = (wid & 1) * 64;    // wave col offset in tile
    const int quad = lane >> 4;
    const int l16  = lane & 15;

    v4f acc[4][4];
    #pragma unroll
    for (int i = 0; i < 4; ++i)
        #pragma unroll
        for (int j = 0; j < 4; ++j)
            acc[i][j] = (v4f){0.f, 0.f, 0.f, 0.f};

    for (int k0 = 0; k0 < K; k0 += 32) {
        #pragma unroll
        for (int it = 0; it < 2; ++it) {
            const int slot = tid + it * 256;
            const int row  = slot >> 2;
            const int cg   = (slot & 3) << 3;
            __builtin_amdgcn_global_load_lds(
                (const __attribute__((address_space(1))) void*)
                    (Bb + (size_t)(n0 + row) * (size_t)ldb + (size_t)(k0 + cg)),
                (__attribute__((address_space(3))) void*)((char*)&sB[0][0] + slot * 16),
                16, 0, 0);
            if constexpr (sizeof(AT) == 2) {
                __builtin_amdgcn_global_load_lds(
                    (const __attribute__((address_space(1))) void*)
                        ((const u16*)Ab + (size_t)(m0 + row) * (size_t)lda + (size_t)(k0 + cg)),
                    (__attribute__((address_space(3))) void*)((char*)&sA[0][0] + slot * 16),
                    16, 0, 0);
            } else {
                *(v8s*)&sA[row][cg] =
                    load8f((const float*)Ab + (size_t)(m0 + row) * (size_t)lda + (size_t)(k0 + cg));
            }
        }
        __syncthreads();

        // fragments: A[m=lane&15][k=quad*8+j]; B mirrors A for the Bt form
        v8s af[4], bfr[4];
        #pragma unroll
        for (int i = 0; i < 4; ++i) {
            af[i]  = *(const v8s*)&sA[wm + i * 16 + l16][quad * 8];
            bfr[i] = *(const v8s*)&sB[wn + i * 16 + l16][quad * 8];
        }
        #pragma unroll
        for (int i = 0; i < 4; ++i)
            #pragma unroll
            for (int j = 0; j < 4; ++j)
                acc[i][j] = __builtin_amdgcn_mfma_f32_16x16x32_bf16(af[i], bfr[j], acc[i][j], 0, 0, 0);
        __syncthreads();
    }

    // C/D layout (m89-verified): col = lane&15, row = quad*4 + reg
    #pragma unroll
    for (int i = 0; i < 4; ++i) {
        int rbase = m0 + wm + i * 16 + quad * 4;
        #pragma unroll
        for (int j = 0; j < 4; ++j) {
            int gcol = n0 + wn + j * 16 + l16;
            #pragma unroll
            for (int r = 0; r < 4; ++r)
                store_out(&Cb[(size_t)(rbase + r) * (size_t)ldc + (size_t)gcol],
                          acc[i][j][r] * alpha);
        }
    }
}

// batched wrapper: batch z decomposed as (z/batDiv, z%batDiv), elem strides
template <typename AT, typename OutT>
__global__ __launch_bounds__(256, 2)
void gemm_fast(const AT* __restrict__ A, const u16* __restrict__ B, OutT* __restrict__ C,
               int K, int lda, int ldb, int ldc, int batDiv,
               long long sAo, long long sAi, long long sBo, long long sBi,
               long long sCo, long long sCi, float alpha)
{
    const int z  = blockIdx.z;
    const int zo = z / batDiv;
    const int zi = z - zo * batDiv;
    gemm_core<AT, OutT>(A + (size_t)zo * (size_t)sAo + (size_t)zi * (size_t)sAi,
                        B + (size_t)zo * (size_t)sBo + (size_t)zi * (size_t)sBi,
                        C + (size_t)zo * (size_t)sCo + (size_t)zi * (size_t)sCi,
                        K, lda, ldb, ldc, alpha, blockIdx.y * 128, blockIdx.x * 128);
}

// all five projections in one launch: z selects (activation, weight, dest)
struct P5 { const u16* a[5]; };
__global__ __launch_bounds__(256, 2)
void gemm_proj5(P5 As, const u16* __restrict__ W, u16* __restrict__ C)
{
    const int z = blockIdx.z;
    gemm_core<u16, bf16>(As.a[z], W + (size_t)z * 1048576ull,
                         (bf16*)(C + (size_t)z * PROJ_ELEMS),
                         1024, 1024, 1024, 1024, 1.f, blockIdx.y * 128, blockIdx.x * 128);
}

// ---------------------------------------------------------------------------
// fp32 -> bf16 batched converter: z selects tensor (all same element count)
// ---------------------------------------------------------------------------
template <int NT> struct CP { const float* p[NT]; };

template <int NT>
__global__ __launch_bounds__(256)
void cvt_batch(CP<NT> ps, u16* __restrict__ dst, int perElems)
{
    const float* s = ps.p[blockIdx.z];
    u16* d = dst + (size_t)blockIdx.z * (size_t)perElems;
    const int i = (blockIdx.x * 256 + threadIdx.x) * 8;
    *(v8s*)(d + i) = load8f(s + i);
}

// ---------------------------------------------------------------------------
// Batched transpose of three projections in one launch.
// per z=(b*8+h): in-view [1024 m][128 d] (row stride 1024, base b*2^20+h*128)
// -> out [z][128 d][1024 m] contiguous.  grid (32,4,96); block (32,8)
// ---------------------------------------------------------------------------
struct T3 { const u16* in[3]; u16* out[3]; };
__global__ __launch_bounds__(256)
void transpose3(T3 t3)
{
    __shared__ u16 tile[32][33];
    const int sel = blockIdx.z >> 5;
    const int z   = blockIdx.z & 31;
    const int b = z >> 3, h = z & 7;
    const u16* ib = t3.in[sel] + (size_t)b * 1048576ull + (size_t)h * 128ull;
    u16* ob = t3.out[sel] + (size_t)z * 131072ull;
    const int m0 = blockIdx.x * 32;
    const int d0 = blockIdx.y * 32;
    const int tx = threadIdx.x;
    const int ty = threadIdx.y;
    #pragma unroll
    for (int i = 0; i < 4; ++i)
        tile[ty + i * 8][tx] = ib[(size_t)(m0 + ty + i * 8) * 1024ull + (size_t)(d0 + tx)];
    __syncthreads();
    #pragma unroll
    for (int i = 0; i < 4; ++i)
        ob[(size_t)(d0 + ty + i * 8) * 1024ull + (size_t)(m0 + tx)] = tile[tx][ty + i * 8];
}

// ---------------------------------------------------------------------------
// Masked softmax over attn_time logits, fp32 in-place in the output region.
// One block per row (32768 rows of 1024); float4/int4 vector loads.
// ---------------------------------------------------------------------------
__global__ __launch_bounds__(256)
void softmax_time(float* __restrict__ P, const int* __restrict__ mask)
{
    const int r  = blockIdx.x;
    const int bh = r >> 10, n = r & 1023;
    const int b  = bh >> 3;
    float4* prow = (float4*)(P + (size_t)r * 1024ull);
    const int4* mrow = (const int4*)(mask + ((size_t)b * 1024ull + (size_t)n) * 1024ull);
    const int t = threadIdx.x;

    float4 x = prow[t];
    const int4 m = mrow[t];
    x.x = m.x ? x.x : -1e9f;
    x.y = m.y ? x.y : -1e9f;
    x.z = m.z ? x.z : -1e9f;
    x.w = m.w ? x.w : -1e9f;

    float mx = fmaxf(fmaxf(x.x, x.y), fmaxf(x.z, x.w));
    #pragma unroll
    for (int o = 32; o; o >>= 1) mx = fmaxf(mx, __shfl_xor(mx, o));
    __shared__ float redm[4], reds[4];
    const int w = t >> 6;
    if ((t & 63) == 0) redm[w] = mx;
    __syncthreads();
    mx = fmaxf(fmaxf(redm[0], redm[1]), fmaxf(redm[2], redm[3]));

    x.x = __expf(x.x - mx); x.y = __expf(x.y - mx);
    x.z = __expf(x.z - mx); x.w = __expf(x.w - mx);
    float s = x.x + x.y + x.z + x.w;
    #pragma unroll
    for (int o = 32; o; o >>= 1) s += __shfl_xor(s, o);
    if ((t & 63) == 0) reds[w] = s;
    __syncthreads();
    s = reds[0] + reds[1] + reds[2] + reds[3];
    const float inv = 1.f / s;
    x.x *= inv; x.y *= inv; x.z *= inv; x.w *= inv;
    prow[t] = x;
}

// ---------------------------------------------------------------------------
// Feature softmax: F fp32 [4096 rows][128] (row r = z*128 + d), softmax over
// last dim -> fp32 attn_feature output AND transposed bf16 FT[z][e][d].
// ---------------------------------------------------------------------------
__global__ __launch_bounds__(128)
void softmax_feat(const float* __restrict__ F, float* __restrict__ out_af, u16* __restrict__ FT)
{
    const int r = blockIdx.x;
    const int z = r >> 7, d = r & 127;
    const int e = threadIdx.x;
    float x = F[(size_t)r * 128ull + e];
    float mx = x;
    #pragma unroll
    for (int o = 32; o; o >>= 1) mx = fmaxf(mx, __shfl_xor(mx, o));
    __shared__ float redm[2], reds[2];
    const int w = e >> 6;
    if ((e & 63) == 0) redm[w] = mx;
    __syncthreads();
    mx = fmaxf(redm[0], redm[1]);
    float ex = __expf(x - mx);
    float s = ex;
    #pragma unroll
    for (int o = 32; o; o >>= 1) s += __shfl_xor(s, o);
    if ((e & 63) == 0) reds[w] = s;
    __syncthreads();
    s = reds[0] + reds[1];
    float p = ex / s;
    out_af[(size_t)r * 128ull + e] = p;
    bf16 pb = __float2bfloat16(p);
    FT[(size_t)z * 16384ull + (size_t)e * 128ull + d] = *(const u16*)&pb;
}

// ---------------------------------------------------------------------------
// out = LayerNorm(fc + v) * gamma + beta ; one block per row; float4 loads
// ---------------------------------------------------------------------------
__global__ __launch_bounds__(256)
void resid_ln(const float* __restrict__ fc, const float* __restrict__ v,
              const float* __restrict__ gamma, const float* __restrict__ beta,
              float* __restrict__ out)
{
    const int r = blockIdx.x;
    const int t = threadIdx.x;
    const float4* fr = (const float4*)(fc + (size_t)r * 1024ull);
    const float4* vr = (const float4*)(v  + (size_t)r * 1024ull);
    float4 a = fr[t], b4 = vr[t];
    float4 x = {a.x + b4.x, a.y + b4.y, a.z + b4.z, a.w + b4.w};
    float s  = x.x + x.y + x.z + x.w;
    float s2 = x.x * x.x + x.y * x.y + x.z * x.z + x.w * x.w;
    #pragma unroll
    for (int o = 32; o; o >>= 1) { s += __shfl_xor(s, o); s2 += __shfl_xor(s2, o); }
    __shared__ float rs[4], rs2[4];
    const int w = t >> 6;
    if ((t & 63) == 0) { rs[w] = s; rs2[w] = s2; }
    __syncthreads();
    s  = rs[0] + rs[1] + rs[2] + rs[3];
    s2 = rs2[0] + rs2[1] + rs2[2] + rs2[3];
    const float mean = s * (1.f / 1024.f);
    const float var  = s2 * (1.f / 1024.f) - mean * mean;
    const float rstd = rsqrtf(var + 1e-6f);
    const float4 g = ((const float4*)gamma)[t];
    const float4 bb = ((const float4*)beta)[t];
    float4 o4 = {(x.x - mean) * rstd * g.x + bb.x,
                 (x.y - mean) * rstd * g.y + bb.y,
                 (x.z - mean) * rstd * g.z + bb.z,
                 (x.w - mean) * rstd * g.w + bb.w};
    ((float4*)(out + (size_t)r * 1024ull))[t] = o4;
}

// ---------------------------------------------------------------------------
extern "C" void kernel_launch(void* const* d_in, const int* in_sizes, int n_in,
                              void* d_out, int out_size, void* d_ws, size_t ws_size,
                              hipStream_t stream)
{
    (void)in_sizes; (void)n_in; (void)out_size; (void)ws_size;
    const float* q_time    = (const float*)d_in[0];
    const float* k_time    = (const float*)d_in[1];
    const float* q_feature = (const float*)d_in[2];
    const float* k_feature = (const float*)d_in[3];
    const float* v_in      = (const float*)d_in[4];
    const int*   mask      = (const int*)d_in[5];
    const float* w_qs_t    = (const float*)d_in[6];
    const float* w_ks_t    = (const float*)d_in[7];
    const float* w_qs_f    = (const float*)d_in[8];
    const float* w_ks_f    = (const float*)d_in[9];
    const float* w_vs      = (const float*)d_in[10];
    const float* w_fc      = (const float*)d_in[11];
    const float* gamma     = (const float*)d_in[12];
    const float* beta      = (const float*)d_in[13];

    // workspace layout (92 MB peak; liveness-aliased)
    char* ws = (char*)d_ws;
    const size_t MB = 1ull << 20;
    u16*   act = (u16*)(ws + 0  * MB);   // 5x8MB converted activations [dead after proj5]
    u16*   wbf = (u16*)(ws + 40 * MB);   // 6x2MB converted weights (w_fc @ +10MB alive to fc)
    u16*   qt  = (u16*)(ws + 52 * MB);   // 5x8MB projections qt,kt,qf,kf,vv
    u16*   vvT = (u16*)(ws + 0  * MB);   // 3x8MB transposed (aliases dead act)
    u16*   qfT = (u16*)(ws + 8  * MB);
    u16*   kfT = (u16*)(ws + 16 * MB);
    u16*   FT  = (u16*)(ws + 24 * MB);   // [32][128e][128d] bf16
    float* F   = (float*)(ws + 25 * MB); // [32][128][128] fp32 feature logits
    u16*   opv = (u16*)(ws + 27 * MB);   // [32][1024][128] bf16
    u16*   o2  = (u16*)(ws + 35 * MB);   // [4096][1024] bf16 (aliases dead w5 tail)
    float* fc  = (float*)(ws + 52 * MB); // [4096][1024] fp32 (aliases dead qt/kt)
    u16*   kt  = qt + PROJ_ELEMS;
    u16*   qf  = kt + PROJ_ELEMS;
    u16*   kf  = qf + PROJ_ELEMS;
    u16*   vv  = kf + PROJ_ELEMS;
    u16*   wfc = wbf + 5ull * 1048576ull;

    float* out0 = (float*)d_out;
    float* oAT  = out0 + PROJ_ELEMS;              // attn_time [4,8,1024,1024] fp32
    float* oAF  = out0 + PROJ_ELEMS + AT_ELEMS;   // attn_feature [4,8,128,128] fp32

    const dim3 blk(256);

    // 0) fp32 -> bf16 conversions (activations, weights)
    {
        CP<5> ca; ca.p[0] = q_time; ca.p[1] = k_time; ca.p[2] = q_feature;
                  ca.p[3] = k_feature; ca.p[4] = v_in;
        cvt_batch<5><<<dim3(2048, 1, 5), blk, 0, stream>>>(ca, act, 4194304);
        CP<6> cw; cw.p[0] = w_qs_t; cw.p[1] = w_ks_t; cw.p[2] = w_qs_f;
                  cw.p[3] = w_ks_f; cw.p[4] = w_vs; cw.p[5] = w_fc;
        cvt_batch<6><<<dim3(512, 1, 6), blk, 0, stream>>>(cw, wbf, 1048576);
    }

    // 1) five projections, one launch: [4096,1024] @ [1024,1024]^T -> bf16
    {
        P5 ps; for (int i = 0; i < 5; ++i) ps.a[i] = act + (size_t)i * PROJ_ELEMS;
        gemm_proj5<<<dim3(8, 32, 5), blk, 0, stream>>>(ps, wbf, qt);
    }

    // 2) transposes vv,qf,kf per-(b,h) [1024,128] -> [128,1024], one launch
    {
        T3 t3; t3.in[0] = vv; t3.in[1] = qf; t3.in[2] = kf;
               t3.out[0] = vvT; t3.out[1] = qfT; t3.out[2] = kfT;
        transpose3<<<dim3(32, 4, 96), dim3(32, 8, 1), 0, stream>>>(t3);
    }

    // 3) time logits: per (b,h) qt[1024,128] @ kt[1024,128]^T * 1/temp -> fp32 oAT
    gemm_fast<<<dim3(8, 8, 32), blk, 0, stream>>>(qt, kt, oAT, 128, 1024, 1024, 1024, 8,
        1048576LL, 128LL, 1048576LL, 128LL, 8388608LL, 1048576LL, INV_TEMP);

    // 4) masked softmax in place (fp32)
    softmax_time<<<32768, 256, 0, stream>>>(oAT, mask);

    // 5) feature logits: per z qfT[128,1024] @ kfT[128,1024]^T * 1/temp -> F fp32
    gemm_fast<<<dim3(1, 1, 32), blk, 0, stream>>>(qfT, kfT, F, 1024, 1024, 1024, 128, 1,
        131072LL, 0LL, 131072LL, 0LL, 16384LL, 0LL, INV_TEMP);

    // 6) feature softmax -> fp32 oAF + transposed bf16 FT
    softmax_feat<<<4096, 128, 0, stream>>>(F, oAF, FT);

    // 7) PV: per z P(fp32)[1024,1024] @ vvT[128,1024]^T -> opv[1024,128] bf16
    gemm_fast<<<dim3(1, 8, 32), blk, 0, stream>>>((const float*)oAT, vvT, (bf16*)opv, 1024,
        1024, 1024, 128, 1, 1048576LL, 0LL, 131072LL, 0LL, 131072LL, 0LL, 1.f);

    // 8) out2: per z=(b,h) opv[1024,128] @ FT[128,128]^T -> [b,n,h,e] bf16
    gemm_fast<<<dim3(1, 8, 32), blk, 0, stream>>>(opv, FT, (bf16*)o2, 128,
        128, 128, 1024, 8, 1048576LL, 131072LL, 131072LL, 16384LL, 1048576LL, 128LL, 1.f);

    // 9) fc: o2(bf16) [4096,1024] @ w_fc(bf16)[1024,1024]^T -> fp32
    gemm_fast<<<dim3(8, 32, 1), blk, 0, stream>>>(o2, wfc, fc, 1024, 1024, 1024, 1024, 1,
        0LL, 0LL, 0LL, 0LL, 0LL, 0LL, 1.f);

    // 10) residual + LayerNorm -> out0 (fp32)
    resid_ln<<<4096, 256, 0, stream>>>(fc, v_in, gamma, beta, out0);
}

// Round 4
// 495.359 us; speedup vs baseline: 1.3232x; 1.0018x over previous
//
#include <hip/hip_runtime.h>
#include <hip/hip_bf16.h>
#include <cstdint>
#include <cstddef>

typedef unsigned short u16;
typedef unsigned int u32;
typedef short v8s __attribute__((ext_vector_type(8)));   // 8 bf16 payloads (4 VGPRs)
typedef float v4f __attribute__((ext_vector_type(4)));
typedef __hip_bfloat16 bf16;

// B=4, N=1024, D=1024, H=8, DK=DV=128
#define PROJ_ELEMS  4194304ull        // 4096*1024
#define AT_ELEMS    33554432ull       // 4*8*1024*1024
#define INV_TEMP    0.08838834764831845f

#define GLOBAL_AS __attribute__((address_space(1)))
#define LDS_AS    __attribute__((address_space(3)))

__device__ __forceinline__ void store_out(float* p, float v) { *p = v; }
__device__ __forceinline__ void store_out(bf16* p, float v) { *p = __float2bfloat16(v); }

// load 8 contiguous fp32 elements, convert to bf16x8 fragment
__device__ __forceinline__ v8s load8f(const float* p) {
    const float4 a = *(const float4*)p;
    const float4 b = *(const float4*)(p + 4);
    v8s r;
    bf16 t;
    t = __float2bfloat16(a.x); r[0] = *(const short*)&t;
    t = __float2bfloat16(a.y); r[1] = *(const short*)&t;
    t = __float2bfloat16(a.z); r[2] = *(const short*)&t;
    t = __float2bfloat16(a.w); r[3] = *(const short*)&t;
    t = __float2bfloat16(b.x); r[4] = *(const short*)&t;
    t = __float2bfloat16(b.y); r[5] = *(const short*)&t;
    t = __float2bfloat16(b.z); r[6] = *(const short*)&t;
    t = __float2bfloat16(b.w); r[7] = *(const short*)&t;
    return r;
}

// ---------------------------------------------------------------------------
// MFMA GEMM core:  C[128x128 tile] = alpha * A[M,K] @ B[N,K]^T   (bf16 A/B)
// Staged via global_load_lds width=16 (m97 fast path), unpadded [128][32].
// ---------------------------------------------------------------------------
template <typename AT, typename OutT>
__device__ __forceinline__ void gemm_core(
    const AT* __restrict__ Ab, const u16* __restrict__ Bb, OutT* __restrict__ Cb,
    int K, int lda, int ldb, int ldc, float alpha, int m0, int n0)
{
    __shared__ __align__(16) u16 sA[128][32];
    __shared__ __align__(16) u16 sB[128][32];

    const int tid  = threadIdx.x;
    const int lane = tid & 63;
    const int wid  = tid >> 6;
    const int wm = (wid >> 1) * 64;
    const int wn = (wid & 1) * 64;
    const int quad = lane >> 4;
    const int l16  = lane & 15;

    v4f acc[4][4];
    #pragma unroll
    for (int i = 0; i < 4; ++i)
        #pragma unroll
        for (int j = 0; j < 4; ++j)
            acc[i][j] = (v4f){0.f, 0.f, 0.f, 0.f};

    for (int k0 = 0; k0 < K; k0 += 32) {
        #pragma unroll
        for (int it = 0; it < 2; ++it) {
            const int slot = tid + it * 256;
            const int row  = slot >> 2;
            const int cg   = (slot & 3) << 3;
            __builtin_amdgcn_global_load_lds(
                (const GLOBAL_AS void*)(Bb + (size_t)(n0 + row) * (size_t)ldb + (size_t)(k0 + cg)),
                (LDS_AS void*)((char*)&sB[0][0] + slot * 16), 16, 0, 0);
            if constexpr (sizeof(AT) == 2) {
                __builtin_amdgcn_global_load_lds(
                    (const GLOBAL_AS void*)((const u16*)Ab + (size_t)(m0 + row) * (size_t)lda + (size_t)(k0 + cg)),
                    (LDS_AS void*)((char*)&sA[0][0] + slot * 16), 16, 0, 0);
            } else {
                *(v8s*)&sA[row][cg] =
                    load8f((const float*)Ab + (size_t)(m0 + row) * (size_t)lda + (size_t)(k0 + cg));
            }
        }
        __syncthreads();

        v8s af[4], bfr[4];
        #pragma unroll
        for (int i = 0; i < 4; ++i) {
            af[i]  = *(const v8s*)&sA[wm + i * 16 + l16][quad * 8];
            bfr[i] = *(const v8s*)&sB[wn + i * 16 + l16][quad * 8];
        }
        #pragma unroll
        for (int i = 0; i < 4; ++i)
            #pragma unroll
            for (int j = 0; j < 4; ++j)
                acc[i][j] = __builtin_amdgcn_mfma_f32_16x16x32_bf16(af[i], bfr[j], acc[i][j], 0, 0, 0);
        __syncthreads();
    }

    // C/D layout (m89-verified): col = lane&15, row = quad*4 + reg
    #pragma unroll
    for (int i = 0; i < 4; ++i) {
        int rbase = m0 + wm + i * 16 + quad * 4;
        #pragma unroll
        for (int j = 0; j < 4; ++j) {
            int gcol = n0 + wn + j * 16 + l16;
            #pragma unroll
            for (int r = 0; r < 4; ++r)
                store_out(&Cb[(size_t)(rbase + r) * (size_t)ldc + (size_t)gcol],
                          acc[i][j][r] * alpha);
        }
    }
}

template <typename AT, typename OutT>
__global__ __launch_bounds__(256, 2)
void gemm_fast(const AT* __restrict__ A, const u16* __restrict__ B, OutT* __restrict__ C,
               int K, int lda, int ldb, int ldc, int batDiv,
               long long sAo, long long sAi, long long sBo, long long sBi,
               long long sCo, long long sCi, float alpha)
{
    const int z  = blockIdx.z;
    const int zo = z / batDiv;
    const int zi = z - zo * batDiv;
    gemm_core<AT, OutT>(A + (size_t)zo * (size_t)sAo + (size_t)zi * (size_t)sAi,
                        B + (size_t)zo * (size_t)sBo + (size_t)zi * (size_t)sBi,
                        C + (size_t)zo * (size_t)sCo + (size_t)zi * (size_t)sCi,
                        K, lda, ldb, ldc, alpha, blockIdx.y * 128, blockIdx.x * 128);
}

// all five projections in one launch
struct P5 { const u16* a[5]; };
__global__ __launch_bounds__(256, 2)
void gemm_proj5(P5 As, const u16* __restrict__ W, u16* __restrict__ C)
{
    const int z = blockIdx.z;
    gemm_core<u16, bf16>(As.a[z], W + (size_t)z * 1048576ull,
                         (bf16*)(C + (size_t)z * PROJ_ELEMS),
                         1024, 1024, 1024, 1024, 1.f, blockIdx.y * 128, blockIdx.x * 128);
}

// feature logits, split-K: grid (8 kc, 32 z); partial [z]128x128 over K=128
__global__ __launch_bounds__(256, 2)
void gemm_feat_sk(const u16* __restrict__ qfT, const u16* __restrict__ kfT, float* __restrict__ Fp)
{
    const int kc = blockIdx.x, z = blockIdx.y;
    gemm_core<u16, float>(qfT + (size_t)z * 131072ull + (size_t)kc * 128ull,
                          kfT + (size_t)z * 131072ull + (size_t)kc * 128ull,
                          Fp + ((size_t)kc * 32 + z) * 16384ull,
                          128, 1024, 1024, 128, INV_TEMP, 0, 0);
}

// ---------------------------------------------------------------------------
// fp32 -> bf16 batched converter
// ---------------------------------------------------------------------------
template <int NT> struct CP { const float* p[NT]; };

template <int NT>
__global__ __launch_bounds__(256)
void cvt_batch(CP<NT> ps, u16* __restrict__ dst, int perElems)
{
    const float* s = ps.p[blockIdx.z];
    u16* d = dst + (size_t)blockIdx.z * (size_t)perElems;
    const int i = (blockIdx.x * 256 + threadIdx.x) * 8;
    *(v8s*)(d + i) = load8f(s + i);
}

// ---------------------------------------------------------------------------
// mask -> bit pack: word w covers flat elements w*32..w*32+31 of mask[4][1024][1024]
// ---------------------------------------------------------------------------
__global__ __launch_bounds__(256)
void mask_pack(const int* __restrict__ mask, u32* __restrict__ mb)
{
    const int w = blockIdx.x * 256 + threadIdx.x;   // 131072 words
    const int* src = mask + (size_t)w * 32ull;
    u32 bits = 0;
    #pragma unroll
    for (int i = 0; i < 32; i += 4) {
        int4 v = *(const int4*)(src + i);
        bits |= (u32)(v.x != 0) << i;
        bits |= (u32)(v.y != 0) << (i + 1);
        bits |= (u32)(v.z != 0) << (i + 2);
        bits |= (u32)(v.w != 0) << (i + 3);
    }
    mb[w] = bits;
}

// ---------------------------------------------------------------------------
// Batched transpose of three projections: per z=(b*8+h) [1024 m][128 d] view
// -> [z][128 d][1024 m] contiguous.
// ---------------------------------------------------------------------------
struct T3 { const u16* in[3]; u16* out[3]; };
__global__ __launch_bounds__(256)
void transpose3(T3 t3)
{
    __shared__ u16 tile[32][33];
    const int sel = blockIdx.z >> 5;
    const int z   = blockIdx.z & 31;
    const int b = z >> 3, h = z & 7;
    const u16* ib = t3.in[sel] + (size_t)b * 1048576ull + (size_t)h * 128ull;
    u16* ob = t3.out[sel] + (size_t)z * 131072ull;
    const int m0 = blockIdx.x * 32;
    const int d0 = blockIdx.y * 32;
    const int tx = threadIdx.x;
    const int ty = threadIdx.y;
    #pragma unroll
    for (int i = 0; i < 4; ++i)
        tile[ty + i * 8][tx] = ib[(size_t)(m0 + ty + i * 8) * 1024ull + (size_t)(d0 + tx)];
    __syncthreads();
    #pragma unroll
    for (int i = 0; i < 4; ++i)
        ob[(size_t)(d0 + ty + i * 8) * 1024ull + (size_t)(m0 + tx)] = tile[tx][ty + i * 8];
}

// ---------------------------------------------------------------------------
// Fused attention: per block (z, 128-row tile):
//   S = qt @ kt^T * invtemp, masked; two-pass online softmax (M,L in pass A,
//   recompute + prob-write + PV accumulate in pass B).
// Writes probs fp32 to oAT and P@V bf16 to opv.
// grid (8 m-tiles, 32 z), block 256.  LDS ~84 KB -> 1 block/CU.
// ---------------------------------------------------------------------------
__global__ __launch_bounds__(256, 1)
void fused_attn(const u16* __restrict__ qt, const u16* __restrict__ kt,
                const u16* __restrict__ vvT, const u32* __restrict__ mb,
                float* __restrict__ oAT, u16* __restrict__ opv)
{
    __shared__ __align__(16) u16 sQ[4][128][32];   // resident Q tile (k-step major)
    __shared__ __align__(16) u16 sK[128][32];      // per-kstep K tile
    __shared__ __align__(16) u16 sV[128][32];      // per-kstep V^T tile
    __shared__ __align__(16) u16 sP[4][128][32];   // bf16 probs tile (k-step major)
    __shared__ float Mld[128], Lld[128], redT[128];
    __shared__ u32 smw[128][4];                    // mask words for current tile

    const int z = blockIdx.y;
    const int b = z >> 3, h = z & 7;
    const int m0 = blockIdx.x * 128;
    const u16* qb = qt + (size_t)b * 1048576ull + (size_t)h * 128ull;
    const u16* kb = kt + (size_t)b * 1048576ull + (size_t)h * 128ull;
    const u16* vb = vvT + (size_t)z * 131072ull;
    float* Ob = oAT + (size_t)z * 1048576ull;
    const u32* mbb = mb + (size_t)b * 32768ull;

    const int tid = threadIdx.x;
    const int lane = tid & 63, wid = tid >> 6;
    const int wm = (wid >> 1) * 64, wn = (wid & 1) * 64;
    const int quad = lane >> 4, l16 = lane & 15;
    const int wnw = wn >> 5;                       // mask word base for this wave

    if (tid < 128) { Mld[tid] = -3.0e38f; Lld[tid] = 0.f; }

    // stage resident Q tile (8 x 16B per thread)
    #pragma unroll
    for (int ks = 0; ks < 4; ++ks)
        #pragma unroll
        for (int it = 0; it < 2; ++it) {
            const int slot = tid + it * 256;
            const int row = slot >> 2, cg = (slot & 3) << 3;
            __builtin_amdgcn_global_load_lds(
                (const GLOBAL_AS void*)(qb + (size_t)(m0 + row) * 1024ull + ks * 32 + cg),
                (LDS_AS void*)((char*)&sQ[ks][0][0] + slot * 16), 16, 0, 0);
        }

    // ---------------- PASS A: row max M and row sum L ----------------
    for (int nt = 0; nt < 8; ++nt) {
        v4f acc[4][4];
        #pragma unroll
        for (int i = 0; i < 4; ++i)
            #pragma unroll
            for (int j = 0; j < 4; ++j)
                acc[i][j] = (v4f){0.f, 0.f, 0.f, 0.f};

        #pragma unroll
        for (int ks = 0; ks < 4; ++ks) {
            #pragma unroll
            for (int it = 0; it < 2; ++it) {
                const int slot = tid + it * 256;
                const int row = slot >> 2, cg = (slot & 3) << 3;
                __builtin_amdgcn_global_load_lds(
                    (const GLOBAL_AS void*)(kb + (size_t)(nt * 128 + row) * 1024ull + ks * 32 + cg),
                    (LDS_AS void*)((char*)&sK[0][0] + slot * 16), 16, 0, 0);
            }
            __syncthreads();
            v8s af[4], bfr[4];
            #pragma unroll
            for (int i = 0; i < 4; ++i) {
                af[i]  = *(const v8s*)&sQ[ks][wm + i * 16 + l16][quad * 8];
                bfr[i] = *(const v8s*)&sK[wn + i * 16 + l16][quad * 8];
            }
            #pragma unroll
            for (int i = 0; i < 4; ++i)
                #pragma unroll
                for (int j = 0; j < 4; ++j)
                    acc[i][j] = __builtin_amdgcn_mfma_f32_16x16x32_bf16(af[i], bfr[j], acc[i][j], 0, 0, 0);
            __syncthreads();
        }

        // stage mask words (2 KB) for this tile
        {
            const int row = tid >> 1, w0 = (tid & 1) * 2;
            *(uint2*)&smw[row][w0] = *(const uint2*)(mbb + (size_t)(m0 + row) * 32ull + nt * 4 + w0);
        }
        __syncthreads();

        // mask + scale; per-row tile max
        float tm[4][4];
        #pragma unroll
        for (int i = 0; i < 4; ++i)
            #pragma unroll
            for (int r = 0; r < 4; ++r) {
                tm[i][r] = -3.0e38f;
                const int rowl = wm + i * 16 + quad * 4 + r;
                #pragma unroll
                for (int j = 0; j < 4; ++j) {
                    const u32 word = smw[rowl][wnw + (j >> 1)];
                    const int bit = ((j & 1) << 4) + l16;
                    float s = acc[i][j][r] * INV_TEMP;
                    s = ((word >> bit) & 1u) ? s : -1e9f;
                    acc[i][j][r] = s;
                    tm[i][r] = fmaxf(tm[i][r], s);
                }
                #pragma unroll
                for (int m = 1; m <= 8; m <<= 1)
                    tm[i][r] = fmaxf(tm[i][r], __shfl_xor(tm[i][r], m));
            }

        if ((wid & 1) && l16 == 0) {
            #pragma unroll
            for (int i = 0; i < 4; ++i)
                #pragma unroll
                for (int r = 0; r < 4; ++r)
                    redT[wm + i * 16 + quad * 4 + r] = tm[i][r];
        }
        __syncthreads();

        float scl[4][4];
        if (!(wid & 1) && l16 == 0) {
            #pragma unroll
            for (int i = 0; i < 4; ++i)
                #pragma unroll
                for (int r = 0; r < 4; ++r) {
                    const int rowl = wm + i * 16 + quad * 4 + r;
                    const float full = fmaxf(tm[i][r], redT[rowl]);
                    const float oldM = Mld[rowl];
                    const float newM = fmaxf(oldM, full);
                    Mld[rowl] = newM;
                    scl[i][r] = __expf(oldM - newM);
                }
        }
        __syncthreads();   // Mld updated, redT free

        // per-row tile sum of exp(s - M)
        float ts[4][4];
        #pragma unroll
        for (int i = 0; i < 4; ++i)
            #pragma unroll
            for (int r = 0; r < 4; ++r) {
                const int rowl = wm + i * 16 + quad * 4 + r;
                const float Mv = Mld[rowl];
                float t = 0.f;
                #pragma unroll
                for (int j = 0; j < 4; ++j)
                    t += __expf(acc[i][j][r] - Mv);
                #pragma unroll
                for (int m = 1; m <= 8; m <<= 1)
                    t += __shfl_xor(t, m);
                ts[i][r] = t;
            }
        if ((wid & 1) && l16 == 0) {
            #pragma unroll
            for (int i = 0; i < 4; ++i)
                #pragma unroll
                for (int r = 0; r < 4; ++r)
                    redT[wm + i * 16 + quad * 4 + r] = ts[i][r];
        }
        __syncthreads();
        if (!(wid & 1) && l16 == 0) {
            #pragma unroll
            for (int i = 0; i < 4; ++i)
                #pragma unroll
                for (int r = 0; r < 4; ++r) {
                    const int rowl = wm + i * 16 + quad * 4 + r;
                    Lld[rowl] = Lld[rowl] * scl[i][r] + ts[i][r] + redT[rowl];
                }
        }
        __syncthreads();
    }

    // per-lane M, 1/L for this lane's 16 rows
    float Mr[16], IL[16];
    #pragma unroll
    for (int i = 0; i < 4; ++i)
        #pragma unroll
        for (int r = 0; r < 4; ++r) {
            const int rowl = wm + i * 16 + quad * 4 + r;
            Mr[i * 4 + r] = Mld[rowl];
            IL[i * 4 + r] = 1.f / Lld[rowl];
        }

    v4f pacc[4][4];
    #pragma unroll
    for (int i = 0; i < 4; ++i)
        #pragma unroll
        for (int j = 0; j < 4; ++j)
            pacc[i][j] = (v4f){0.f, 0.f, 0.f, 0.f};

    // ---------------- PASS B: probs out + PV accumulate ----------------
    for (int nt = 0; nt < 8; ++nt) {
        v4f acc[4][4];
        #pragma unroll
        for (int i = 0; i < 4; ++i)
            #pragma unroll
            for (int j = 0; j < 4; ++j)
                acc[i][j] = (v4f){0.f, 0.f, 0.f, 0.f};

        #pragma unroll
        for (int ks = 0; ks < 4; ++ks) {
            #pragma unroll
            for (int it = 0; it < 2; ++it) {
                const int slot = tid + it * 256;
                const int row = slot >> 2, cg = (slot & 3) << 3;
                __builtin_amdgcn_global_load_lds(
                    (const GLOBAL_AS void*)(kb + (size_t)(nt * 128 + row) * 1024ull + ks * 32 + cg),
                    (LDS_AS void*)((char*)&sK[0][0] + slot * 16), 16, 0, 0);
            }
            __syncthreads();
            v8s af[4], bfr[4];
            #pragma unroll
            for (int i = 0; i < 4; ++i) {
                af[i]  = *(const v8s*)&sQ[ks][wm + i * 16 + l16][quad * 8];
                bfr[i] = *(const v8s*)&sK[wn + i * 16 + l16][quad * 8];
            }
            #pragma unroll
            for (int i = 0; i < 4; ++i)
                #pragma unroll
                for (int j = 0; j < 4; ++j)
                    acc[i][j] = __builtin_amdgcn_mfma_f32_16x16x32_bf16(af[i], bfr[j], acc[i][j], 0, 0, 0);
            __syncthreads();
        }

        {
            const int row = tid >> 1, w0 = (tid & 1) * 2;
            *(uint2*)&smw[row][w0] = *(const uint2*)(mbb + (size_t)(m0 + row) * 32ull + nt * 4 + w0);
        }
        __syncthreads();

        // probs: write fp32 out + bf16 into sP
        #pragma unroll
        for (int i = 0; i < 4; ++i)
            #pragma unroll
            for (int r = 0; r < 4; ++r) {
                const int rowl = wm + i * 16 + quad * 4 + r;
                const int idx = i * 4 + r;
                #pragma unroll
                for (int j = 0; j < 4; ++j) {
                    const u32 word = smw[rowl][wnw + (j >> 1)];
                    const int bit = ((j & 1) << 4) + l16;
                    float s = acc[i][j][r] * INV_TEMP;
                    s = ((word >> bit) & 1u) ? s : -1e9f;
                    const float p = __expf(s - Mr[idx]) * IL[idx];
                    const int c = wn + j * 16 + l16;
                    Ob[(size_t)(m0 + rowl) * 1024ull + nt * 128 + c] = p;
                    bf16 pb = __float2bfloat16(p);
                    sP[c >> 5][rowl][c & 31] = *(const u16*)&pb;
                }
            }
        __syncthreads();   // sP complete

        // PV accumulate over this tile's 128 k
        #pragma unroll
        for (int ks = 0; ks < 4; ++ks) {
            #pragma unroll
            for (int it = 0; it < 2; ++it) {
                const int slot = tid + it * 256;
                const int row = slot >> 2, cg = (slot & 3) << 3;
                __builtin_amdgcn_global_load_lds(
                    (const GLOBAL_AS void*)(vb + (size_t)row * 1024ull + nt * 128 + ks * 32 + cg),
                    (LDS_AS void*)((char*)&sV[0][0] + slot * 16), 16, 0, 0);
            }
            __syncthreads();
            v8s af[4], bfr[4];
            #pragma unroll
            for (int i = 0; i < 4; ++i) {
                af[i]  = *(const v8s*)&sP[ks][wm + i * 16 + l16][quad * 8];
                bfr[i] = *(const v8s*)&sV[wn + i * 16 + l16][quad * 8];
            }
            #pragma unroll
            for (int i = 0; i < 4; ++i)
                #pragma unroll
                for (int j = 0; j < 4; ++j)
                    pacc[i][j] = __builtin_amdgcn_mfma_f32_16x16x32_bf16(af[i], bfr[j], pacc[i][j], 0, 0, 0);
            __syncthreads();
        }
    }

    // epilogue: opv[z][m][e] bf16
    u16* opvB = opv + (size_t)z * 131072ull;
    #pragma unroll
    for (int i = 0; i < 4; ++i) {
        const int rbase = m0 + wm + i * 16 + quad * 4;
        #pragma unroll
        for (int j = 0; j < 4; ++j) {
            const int e = wn + j * 16 + l16;
            #pragma unroll
            for (int r = 0; r < 4; ++r) {
                bf16 t = __float2bfloat16(pacc[i][j][r]);
                opvB[(size_t)(rbase + r) * 128ull + e] = *(const u16*)&t;
            }
        }
    }
}

// ---------------------------------------------------------------------------
// Feature softmax with split-K reduction: Fp [8 kc][32 z][128 d][128 e] ->
// softmax rows -> fp32 attn_feature output AND transposed bf16 FT[z][e][d].
// ---------------------------------------------------------------------------
__global__ __launch_bounds__(128)
void softmax_feat(const float* __restrict__ Fp, float* __restrict__ out_af, u16* __restrict__ FT)
{
    const int r = blockIdx.x;
    const int z = r >> 7, d = r & 127;
    const int e = threadIdx.x;
    float x = 0.f;
    #pragma unroll
    for (int kc = 0; kc < 8; ++kc)
        x += Fp[((size_t)kc * 32 + z) * 16384ull + (size_t)d * 128ull + e];
    float mx = x;
    #pragma unroll
    for (int o = 32; o; o >>= 1) mx = fmaxf(mx, __shfl_xor(mx, o));
    __shared__ float redm[2], reds[2];
    const int w = e >> 6;
    if ((e & 63) == 0) redm[w] = mx;
    __syncthreads();
    mx = fmaxf(redm[0], redm[1]);
    float ex = __expf(x - mx);
    float s = ex;
    #pragma unroll
    for (int o = 32; o; o >>= 1) s += __shfl_xor(s, o);
    if ((e & 63) == 0) reds[w] = s;
    __syncthreads();
    s = reds[0] + reds[1];
    float p = ex / s;
    out_af[(size_t)r * 128ull + e] = p;
    bf16 pb = __float2bfloat16(p);
    FT[(size_t)z * 16384ull + (size_t)e * 128ull + d] = *(const u16*)&pb;
}

// ---------------------------------------------------------------------------
// out = LayerNorm(fc + v) * gamma + beta ; one block per row; float4 loads
// ---------------------------------------------------------------------------
__global__ __launch_bounds__(256)
void resid_ln(const float* __restrict__ fc, const float* __restrict__ v,
              const float* __restrict__ gamma, const float* __restrict__ beta,
              float* __restrict__ out)
{
    const int r = blockIdx.x;
    const int t = threadIdx.x;
    const float4* fr = (const float4*)(fc + (size_t)r * 1024ull);
    const float4* vr = (const float4*)(v  + (size_t)r * 1024ull);
    float4 a = fr[t], b4 = vr[t];
    float4 x = {a.x + b4.x, a.y + b4.y, a.z + b4.z, a.w + b4.w};
    float s  = x.x + x.y + x.z + x.w;
    float s2 = x.x * x.x + x.y * x.y + x.z * x.z + x.w * x.w;
    #pragma unroll
    for (int o = 32; o; o >>= 1) { s += __shfl_xor(s, o); s2 += __shfl_xor(s2, o); }
    __shared__ float rs[4], rs2[4];
    const int w = t >> 6;
    if ((t & 63) == 0) { rs[w] = s; rs2[w] = s2; }
    __syncthreads();
    s  = rs[0] + rs[1] + rs[2] + rs[3];
    s2 = rs2[0] + rs2[1] + rs2[2] + rs2[3];
    const float mean = s * (1.f / 1024.f);
    const float var  = s2 * (1.f / 1024.f) - mean * mean;
    const float rstd = rsqrtf(var + 1e-6f);
    const float4 g = ((const float4*)gamma)[t];
    const float4 bb = ((const float4*)beta)[t];
    float4 o4 = {(x.x - mean) * rstd * g.x + bb.x,
                 (x.y - mean) * rstd * g.y + bb.y,
                 (x.z - mean) * rstd * g.z + bb.z,
                 (x.w - mean) * rstd * g.w + bb.w};
    ((float4*)(out + (size_t)r * 1024ull))[t] = o4;
}

// ---------------------------------------------------------------------------
extern "C" void kernel_launch(void* const* d_in, const int* in_sizes, int n_in,
                              void* d_out, int out_size, void* d_ws, size_t ws_size,
                              hipStream_t stream)
{
    (void)in_sizes; (void)n_in; (void)out_size; (void)ws_size;
    const float* q_time    = (const float*)d_in[0];
    const float* k_time    = (const float*)d_in[1];
    const float* q_feature = (const float*)d_in[2];
    const float* k_feature = (const float*)d_in[3];
    const float* v_in      = (const float*)d_in[4];
    const int*   mask      = (const int*)d_in[5];
    const float* w_qs_t    = (const float*)d_in[6];
    const float* w_ks_t    = (const float*)d_in[7];
    const float* w_qs_f    = (const float*)d_in[8];
    const float* w_ks_f    = (const float*)d_in[9];
    const float* w_vs      = (const float*)d_in[10];
    const float* w_fc      = (const float*)d_in[11];
    const float* gamma     = (const float*)d_in[12];
    const float* beta      = (const float*)d_in[13];

    // workspace layout (93 MB peak; liveness-aliased):
    //  0..40   act (5x8MB)              [dead after proj5]
    // 40..52   wbf (6x2MB; wfc 50..52 alive until fc)
    // 52..92   qt,kt,qf,kf,vv (5x8MB)   [qf,kf dead after transpose3; vv after transpose3;
    //                                    qt,kt dead after fused_attn]
    //  0..8    vvT    (aliases act)
    //  8..16   qfT
    // 16..24   kfT
    // 24..25   FT
    // 25..41   Fp (8x2MB fp32 partials; aliases act tail + dead wbf[40..42])
    // 41..49   opv (aliases dead wbf/act region)
    // 52..60   o2  (aliases dead qt)
    // 60..76   fc  (aliases dead kt,qf)
    // 92..92.5 mb  (mask bits, virgin region)
    char* ws = (char*)d_ws;
    const size_t MB = 1ull << 20;
    u16*   act = (u16*)(ws + 0  * MB);
    u16*   wbf = (u16*)(ws + 40 * MB);
    u16*   qt  = (u16*)(ws + 52 * MB);
    u16*   vvT = (u16*)(ws + 0  * MB);
    u16*   qfT = (u16*)(ws + 8  * MB);
    u16*   kfT = (u16*)(ws + 16 * MB);
    u16*   FT  = (u16*)(ws + 24 * MB);
    float* Fp  = (float*)(ws + 25 * MB);
    u16*   opv = (u16*)(ws + 41 * MB);
    u16*   o2  = (u16*)(ws + 52 * MB);
    float* fc  = (float*)(ws + 60 * MB);
    u32*   mb  = (u32*)(ws + 92 * MB);
    u16*   kt  = qt + PROJ_ELEMS;
    u16*   qf  = kt + PROJ_ELEMS;
    u16*   kf  = qf + PROJ_ELEMS;
    u16*   vv  = kf + PROJ_ELEMS;
    u16*   wfc = wbf + 5ull * 1048576ull;

    float* out0 = (float*)d_out;
    float* oAT  = out0 + PROJ_ELEMS;              // attn_time [4,8,1024,1024] fp32
    float* oAF  = out0 + PROJ_ELEMS + AT_ELEMS;   // attn_feature [4,8,128,128] fp32

    const dim3 blk(256);

    // 0) fp32 -> bf16 conversions + mask bit-pack
    {
        CP<5> ca; ca.p[0] = q_time; ca.p[1] = k_time; ca.p[2] = q_feature;
                  ca.p[3] = k_feature; ca.p[4] = v_in;
        cvt_batch<5><<<dim3(2048, 1, 5), blk, 0, stream>>>(ca, act, 4194304);
        CP<6> cw; cw.p[0] = w_qs_t; cw.p[1] = w_ks_t; cw.p[2] = w_qs_f;
                  cw.p[3] = w_ks_f; cw.p[4] = w_vs; cw.p[5] = w_fc;
        cvt_batch<6><<<dim3(512, 1, 6), blk, 0, stream>>>(cw, wbf, 1048576);
        mask_pack<<<512, blk, 0, stream>>>(mask, mb);
    }

    // 1) five projections, one launch
    {
        P5 ps; for (int i = 0; i < 5; ++i) ps.a[i] = act + (size_t)i * PROJ_ELEMS;
        gemm_proj5<<<dim3(8, 32, 5), blk, 0, stream>>>(ps, wbf, qt);
    }

    // 2) transposes vv,qf,kf -> vvT,qfT,kfT
    {
        T3 t3; t3.in[0] = vv; t3.in[1] = qf; t3.in[2] = kf;
               t3.out[0] = vvT; t3.out[1] = qfT; t3.out[2] = kfT;
        transpose3<<<dim3(32, 4, 96), dim3(32, 8, 1), 0, stream>>>(t3);
    }

    // 3) feature logits (split-K x8) -> Fp partials
    gemm_feat_sk<<<dim3(8, 32), blk, 0, stream>>>(qfT, kfT, Fp);

    // 4) feature softmax (+split-K reduce) -> oAF fp32 + FT bf16
    softmax_feat<<<4096, 128, 0, stream>>>(Fp, oAF, FT);

    // 5) fused attention: logits+mask+softmax -> oAT fp32; P@V -> opv bf16
    fused_attn<<<dim3(8, 32), blk, 0, stream>>>(qt, kt, vvT, mb, oAT, opv);

    // 6) out2: per z=(b,h) opv[1024,128] @ FT[128,128]^T -> [b,n,h,e] bf16
    gemm_fast<<<dim3(1, 8, 32), blk, 0, stream>>>(opv, FT, (bf16*)o2, 128,
        128, 128, 1024, 8, 1048576LL, 131072LL, 131072LL, 16384LL, 1048576LL, 128LL, 1.f);

    // 7) fc: o2(bf16) @ w_fc(bf16)^T -> fp32
    gemm_fast<<<dim3(8, 32, 1), blk, 0, stream>>>(o2, wfc, fc, 1024, 1024, 1024, 1024, 1,
        0LL, 0LL, 0LL, 0LL, 0LL, 0LL, 1.f);

    // 8) residual + LayerNorm -> out0
    resid_ln<<<4096, 256, 0, stream>>>(fc, v_in, gamma, beta, out0);
}